// Round 1
// baseline (35.043 us; speedup 1.0000x reference)
//
#include <hip/hip_runtime.h>
#include <math.h>

#define ALPHA 0.001f
#define BETA  0.001f
#define EPS   1e-32f

constexpr int BLOCK  = 256;
constexpr int JCHUNK = 2048;   // j-tile staged in LDS (8 KB)

// Kernel 1: e[i] = log(dur[i]+EPS) - log_h[i]; per-block partials of e^2 and log_h^2.
__global__ void e_kernel(const float* __restrict__ log_h,
                         const float* __restrict__ dur,
                         float* __restrict__ e,
                         float* __restrict__ e2p,
                         float* __restrict__ lh2p,
                         int n) {
    int i = blockIdx.x * BLOCK + threadIdx.x;
    float e2 = 0.f, l2 = 0.f;
    if (i < n) {
        float lh = log_h[i];
        float ei = logf(dur[i] + EPS) - lh;
        e[i] = ei;
        e2 = ei * ei;
        l2 = lh * lh;
    }
    // wave64 reduce
    for (int off = 32; off; off >>= 1) {
        e2 += __shfl_down(e2, off);
        l2 += __shfl_down(l2, off);
    }
    __shared__ float we[BLOCK / 64], wl[BLOCK / 64];
    int tid = threadIdx.x;
    if ((tid & 63) == 0) { we[tid >> 6] = e2; wl[tid >> 6] = l2; }
    __syncthreads();
    if (tid == 0) {
        float te = 0.f, tl = 0.f;
        for (int w = 0; w < BLOCK / 64; ++w) { te += we[w]; tl += wl[w]; }
        e2p[blockIdx.x]  = te;
        lh2p[blockIdx.x] = tl;
    }
}

// Kernel 2: per (i-block, j-chunk) tile, sum relu(e_j - e_i) * events[i].
__global__ void pair_kernel(const float* __restrict__ e,
                            const float* __restrict__ events,
                            float* __restrict__ lossp,
                            int n) {
    __shared__ float se[JCHUNK];
    const int tid = threadIdx.x;
    const int j0  = blockIdx.y * JCHUNK;
    const int jcount = min(JCHUNK, n - j0);

    // stage j-chunk into LDS (vectorized; n is a multiple of 4)
    for (int k = tid; k * 4 < jcount; k += BLOCK) {
        ((float4*)se)[k] = ((const float4*)(e + j0))[k];
    }
    __syncthreads();

    const int i = blockIdx.x * BLOCK + tid;
    const float ei = (i < n) ? e[i] : 0.f;
    const float ev = (i < n) ? events[i] : 0.f;

    float s0 = 0.f, s1 = 0.f, s2 = 0.f, s3 = 0.f;
    const int k4 = jcount >> 2;
    #pragma unroll 4
    for (int k = 0; k < k4; ++k) {
        float4 v = ((const float4*)se)[k];   // uniform addr -> LDS broadcast
        s0 += fmaxf(v.x - ei, 0.f);
        s1 += fmaxf(v.y - ei, 0.f);
        s2 += fmaxf(v.z - ei, 0.f);
        s3 += fmaxf(v.w - ei, 0.f);
    }
    float sum = ((s0 + s1) + (s2 + s3)) * ev;

    for (int off = 32; off; off >>= 1) sum += __shfl_down(sum, off);
    __shared__ float ws[BLOCK / 64];
    if ((tid & 63) == 0) ws[tid >> 6] = sum;
    __syncthreads();
    if (tid == 0) {
        float t = 0.f;
        for (int w = 0; w < BLOCK / 64; ++w) t += ws[w];
        lossp[blockIdx.y * gridDim.x + blockIdx.x] = t;
    }
}

// Kernel 3: combine partials with scaling.
__global__ void finalize_kernel(const float* __restrict__ lossp, int nloss,
                                const float* __restrict__ e2p,
                                const float* __restrict__ lh2p, int nb,
                                float* __restrict__ out, int n) {
    const int tid = threadIdx.x;
    const float invn  = 1.0f / (float)n;
    const float invn2 = invn * invn;
    float v = 0.f;
    for (int k = tid; k < nloss; k += BLOCK) v += lossp[k] * invn2;
    for (int k = tid; k < nb;    k += BLOCK) v += (ALPHA * e2p[k] + BETA * lh2p[k]) * invn;
    for (int off = 32; off; off >>= 1) v += __shfl_down(v, off);
    __shared__ float ws[BLOCK / 64];
    if ((tid & 63) == 0) ws[tid >> 6] = v;
    __syncthreads();
    if (tid == 0) {
        float t = 0.f;
        for (int w = 0; w < BLOCK / 64; ++w) t += ws[w];
        out[0] = t;
    }
}

extern "C" void kernel_launch(void* const* d_in, const int* in_sizes, int n_in,
                              void* d_out, int out_size, void* d_ws, size_t ws_size,
                              hipStream_t stream) {
    const float* log_h  = (const float*)d_in[0];
    const float* dur    = (const float*)d_in[1];
    const float* events = (const float*)d_in[2];
    float* out = (float*)d_out;
    const int n = in_sizes[1];            // 16384

    const int nib = (n + BLOCK  - 1) / BLOCK;    // 64 i-blocks
    const int njc = (n + JCHUNK - 1) / JCHUNK;   // 8 j-chunks

    float* e     = (float*)d_ws;          // n floats (64 KB)
    float* lossp = e + n;                 // nib*njc floats
    float* e2p   = lossp + nib * njc;     // nib floats
    float* lh2p  = e2p + nib;             // nib floats

    e_kernel<<<nib, BLOCK, 0, stream>>>(log_h, dur, e, e2p, lh2p, n);
    dim3 grid(nib, njc);
    pair_kernel<<<grid, BLOCK, 0, stream>>>(e, events, lossp, n);
    finalize_kernel<<<1, BLOCK, 0, stream>>>(lossp, nib * njc, e2p, lh2p, nib, out, n);
}